// Round 7
// baseline (135.288 us; speedup 1.0000x reference)
//
#include <hip/hip_runtime.h>

using u16 = unsigned short;
using u32 = unsigned int;
typedef __attribute__((ext_vector_type(8))) short bf16x8;
typedef __attribute__((ext_vector_type(4))) float f32x4;

__device__ __forceinline__ float bf2f(u16 h) {
  union { u32 u; float f; } c; c.u = (u32)h << 16; return c.f;
}
__device__ __forceinline__ u16 f2bf(float f) {
  union { float f; u32 u; } c; c.f = f;
  u32 u = c.u;
  u32 r = (u + 0x7FFFu + ((u >> 16) & 1u)) >> 16;
  return (u16)r;
}

#define GLD16(gsrc, ldst)                                                      \
  __builtin_amdgcn_global_load_lds(                                            \
      (const __attribute__((address_space(1))) unsigned int*)(gsrc),           \
      (__attribute__((address_space(3))) unsigned int*)(ldst), 16, 0, 0)

// kappa: virtual key order inside a 64-key tile so PV's A-frag is the natural
// register layout of the swapped QK^T output.
__device__ __forceinline__ int kappa(int ss) {
  return (ss & 0x23) | ((ss & 0x10) >> 2) | ((ss & 0x0C) << 1);
}

// ---------------------------------------------------------------- convert
__global__ void cvt_kernel(const float* __restrict__ src, u16* __restrict__ dst, int n) {
  int i = (blockIdx.x * blockDim.x + threadIdx.x) * 4;
  if (i < n) {
    float4 v = *(const float4*)(src + i);
    ushort4 o;
    o.x = f2bf(v.x); o.y = f2bf(v.y); o.z = f2bf(v.z); o.w = f2bf(v.w);
    *(ushort4*)(dst + i) = o;
  }
}

// ---------------------------------------------------------------- rel-pos table
__global__ void tbl_kernel(const float* __restrict__ rph, const float* __restrict__ rpw,
                           u16* __restrict__ tbl) {
  int i = blockIdx.x * 256 + threadIdx.x;  // 8192 total
  int row = i >> 6, d = i & 63;
  float v = 0.f;
  if (row < 63) v = rph[row * 64 + d];
  else if (row >= 64 && row < 127) v = rpw[(row - 64) * 64 + d];
  tbl[i] = f2bf(v * 1.44269504f);
}

// ---------------------------------------------------------------- P gemm
// P[g][j] = q[g][:] . tbl[j][:]   (98304 x 128 x 64), bf16 out (log2 domain)
__global__ __launch_bounds__(256, 2) void pgemm_kernel(
    const u16* __restrict__ A, const u16* __restrict__ tbl, u16* __restrict__ P) {
  __shared__ u16 As[128 * 64];
  __shared__ u16 Bs[128 * 64];
  const int tid = threadIdx.x;
  const int lane = tid & 63, wave = tid >> 6;
  const int lr = lane & 15, lg = lane >> 4;
  const int m0 = blockIdx.x * 128;
  const int wm = (wave >> 1) * 64, wn = (wave & 1) * 64;

#pragma unroll
  for (int i = 0; i < 4; ++i) {
    int c = tid + i * 256;
    int row = c >> 3, pp = c & 7;
    int pl = pp ^ (row & 7);  // pre-swizzled source, linear LDS dest
    GLD16(A + (size_t)(m0 + row) * 64 + pl * 8, &As[c * 8]);
    GLD16(tbl + row * 64 + pl * 8, &Bs[c * 8]);
  }
  __syncthreads();

  bf16x8 a[4][2], b[4][2];
#pragma unroll
  for (int m = 0; m < 4; ++m) {
    int row = wm + m * 16 + lr;
#pragma unroll
    for (int kf = 0; kf < 2; ++kf)
      a[m][kf] = *(const bf16x8*)&As[(row * 64 + kf * 32 + lg * 8) ^ ((row & 7) << 3)];
  }
#pragma unroll
  for (int n = 0; n < 4; ++n) {
    int row = wn + n * 16 + lr;
#pragma unroll
    for (int kf = 0; kf < 2; ++kf)
      b[n][kf] = *(const bf16x8*)&Bs[(row * 64 + kf * 32 + lg * 8) ^ ((row & 7) << 3)];
  }

  f32x4 acc[4][4] = {};
#pragma unroll
  for (int kf = 0; kf < 2; ++kf)
#pragma unroll
    for (int m = 0; m < 4; ++m)
#pragma unroll
      for (int n = 0; n < 4; ++n)
        acc[m][n] = __builtin_amdgcn_mfma_f32_16x16x32_bf16(a[m][kf], b[n][kf], acc[m][n], 0, 0, 0);

#pragma unroll
  for (int m = 0; m < 4; ++m)
#pragma unroll
    for (int n = 0; n < 4; ++n) {
      const int col = wn + n * 16 + lr;
#pragma unroll
      for (int r = 0; r < 4; ++r) {
        const int g = m0 + wm + m * 16 + lg * 4 + r;
        P[(size_t)g * 128 + col] = f2bf(acc[m][n][r]);
      }
    }
}

// ---------------------------------------------------------------- GEMM
// 128x128 tile, BK=64, XOR-swizzled LDS, XCD block swizzle, counted vmcnt,
// loop-carried staging pointers (address calc hoisted out of the K-loop).
template <int MODE>
__global__ __launch_bounds__(256, 2) void gemm128(
    const u16* __restrict__ A, const u16* __restrict__ B,
    const float* __restrict__ bias, u16* __restrict__ oq, u16* __restrict__ ok,
    u16* __restrict__ ovt, float* __restrict__ ofp) {
  __shared__ u16 As[2][128 * 64];
  __shared__ u16 Bs[2][128 * 64];
  const int tid = threadIdx.x;
  const int lane = tid & 63, wave = tid >> 6;
  const int lr = lane & 15, lg = lane >> 4;

  const int nbx = (MODE == 0) ? 18 : 6;
  const int nwg = nbx * 64;
  int id = blockIdx.y * nbx + blockIdx.x;
  int nid = (id & 7) * (nwg >> 3) + (id >> 3);
  const int m0 = (nid / nbx) * 128, n0 = (nid % nbx) * 128;
  const int wm = (wave >> 1) * 64, wn = (wave & 1) * 64;

  f32x4 acc[4][4] = {};

  // loop-carried staging pointers: computed once, advanced by constants
  const u16* ap[4];
  const u16* bp[4];
#pragma unroll
  for (int i = 0; i < 4; ++i) {
    int c = tid + i * 256;          // 1024 chunks = 128 rows x 8
    int row = c >> 3, pp = c & 7;
    int pl = pp ^ (row & 7);        // pre-swizzled global source, linear LDS dest
    if constexpr (MODE == 0) {
      ap[i] = A + (size_t)(m0 + row) * 768 + pl * 8;
    } else {
      int g = m0 + row;
      ap[i] = A + ((size_t)((g >> 10) * 12) << 16) + (g & 1023) * 64 + pl * 8;
    }
    bp[i] = B + (size_t)(n0 + row) * 768 + pl * 8;
  }
  constexpr int dA = (MODE == 0) ? 64 : 65536;

  auto stage = [&](int bi) {
#pragma unroll
    for (int i = 0; i < 4; ++i) {
      int c = tid + i * 256;
      GLD16(ap[i], &As[bi][c * 8]);
      GLD16(bp[i], &Bs[bi][c * 8]);
      ap[i] += dA;
      bp[i] += 64;
    }
  };

  stage(0);
#pragma unroll 1
  for (int t = 0; t < 12; ++t) {
    const int cur = t & 1;
    if (t < 11) {
      stage(cur ^ 1);
      asm volatile("s_waitcnt vmcnt(8)" ::: "memory");
    } else {
      asm volatile("s_waitcnt vmcnt(0)" ::: "memory");
    }
    __builtin_amdgcn_sched_barrier(0);
    __builtin_amdgcn_s_barrier();        // entry: buf[cur] ready for all waves
    __builtin_amdgcn_sched_barrier(0);

    bf16x8 a[4][2], b[4][2];
#pragma unroll
    for (int m = 0; m < 4; ++m) {
      int row = wm + m * 16 + lr;
#pragma unroll
      for (int kf = 0; kf < 2; ++kf)
        a[m][kf] = *(const bf16x8*)&As[cur][(row * 64 + kf * 32 + lg * 8) ^ ((row & 7) << 3)];
    }
#pragma unroll
    for (int n = 0; n < 4; ++n) {
      int row = wn + n * 16 + lr;
#pragma unroll
      for (int kf = 0; kf < 2; ++kf)
        b[n][kf] = *(const bf16x8*)&Bs[cur][(row * 64 + kf * 32 + lg * 8) ^ ((row & 7) << 3)];
    }
    __builtin_amdgcn_s_setprio(1);
#pragma unroll
    for (int kf = 0; kf < 2; ++kf)
#pragma unroll
      for (int m = 0; m < 4; ++m)
#pragma unroll
        for (int n = 0; n < 4; ++n)
          acc[m][n] = __builtin_amdgcn_mfma_f32_16x16x32_bf16(a[m][kf], b[n][kf], acc[m][n], 0, 0, 0);
    __builtin_amdgcn_s_setprio(0);

    __builtin_amdgcn_sched_barrier(0);
    __builtin_amdgcn_s_barrier();        // exit: all reads done before overwrite
    __builtin_amdgcn_sched_barrier(0);
  }

#pragma unroll
  for (int m = 0; m < 4; ++m) {
    const int grow0 = m0 + wm + m * 16 + lg * 4;
#pragma unroll
    for (int n = 0; n < 4; ++n) {
      const int gcol = n0 + wn + n * 16 + lr;
      const float bv = bias[gcol];
      if constexpr (MODE == 0) {
        int which = (gcol >= 1536) ? 2 : (gcol >= 768 ? 1 : 0);
        int rem = gcol - which * 768;
        int bh = (grow0 >> 10) * 12 + (rem >> 6);
        if (which == 2) {
          int s0 = grow0 & 1023;
          int colb = (s0 & ~63) | kappa(s0 & 63);  // kappa keeps low 2 bits
          ushort4 pk;
          pk.x = f2bf(acc[m][n][0] + bv);
          pk.y = f2bf(acc[m][n][1] + bv);
          pk.z = f2bf(acc[m][n][2] + bv);
          pk.w = f2bf(acc[m][n][3] + bv);
          *(ushort4*)&ovt[((size_t)bh << 16) + (size_t)(rem & 63) * 1024 + colb] = pk;
        } else {
          u16* dst = (which == 0) ? oq : ok;
#pragma unroll
          for (int r = 0; r < 4; ++r) {
            int s = (grow0 & 1023) + r;
            dst[((size_t)bh << 16) + s * 64 + (rem & 63)] = f2bf(acc[m][n][r] + bv);
          }
        }
      } else {
#pragma unroll
        for (int r = 0; r < 4; ++r)
          ofp[(size_t)(grow0 + r) * 768 + gcol] = acc[m][n][r] + bv;
      }
    }
  }
}

// ---------------------------------------------------------------- flash attention
// grid (96 heads, 8 q-tiles); block 256 = 4 waves x 32 q-rows
// Swapped QK^T, kappa-permuted V, no online max, counted vmcnt, loop-carried
// staging pointers, software-pipelined rel_h bias loads (issued one tile ahead).
__global__ __launch_bounds__(256, 2) void attn_kernel(
    const u16* __restrict__ qb, const u16* __restrict__ kb,
    const u16* __restrict__ vtb, const u16* __restrict__ pb,
    u16* __restrict__ ao) {
  __shared__ u16 Ks[2][64 * 64];
  __shared__ u16 Vs[2][64 * 64];

  const int tid = threadIdx.x;
  const int lane = tid & 63, wave = tid >> 6;
  const int lr = lane & 15, lg = lane >> 4;
  const int bh = blockIdx.x;   // head fastest -> all q-tiles of a head on one XCD
  const int q0 = blockIdx.y * 128 + wave * 32;
  const size_t hb = (size_t)bh << 16;

  bf16x8 qf[2][2];
#pragma unroll
  for (int m = 0; m < 2; ++m)
#pragma unroll
    for (int kf = 0; kf < 2; ++kf)
      qf[m][kf] = *(const bf16x8*)(qb + hb + (size_t)(q0 + m * 16 + lr) * 64 + kf * 32 + lg * 8);

  // rel_w bias (log2 domain), per lane's own q-row g = q0+m*16+lr
  float rwv[2][2][4];
  const u16* bp[2];  // rel_h bias pointer per m, walks down 2 u16 per tile
#pragma unroll
  for (int m = 0; m < 2; ++m) {
    int g = q0 + m * 16 + lr;
    const size_t pbase = (((size_t)bh << 10) + g) * 128;
    int w = g & 31;
#pragma unroll
    for (int i = 0; i < 2; ++i)
#pragma unroll
      for (int r = 0; r < 4; ++r) {
        int kw = i * 16 + lg * 4 + r;
        rwv[m][i][r] = bf2f(pb[pbase + 95 + w - kw]);
      }
    bp[m] = pb + pbase + (g >> 5) + 31;  // kh0=0 position
  }

  // current-tile rel_h bias values (u16), pipelined one tile ahead
  u16 bc0[2], bc1[2];
#pragma unroll
  for (int m = 0; m < 2; ++m) { bc0[m] = bp[m][0]; bc1[m] = bp[m][-1]; }

  float lsum[2] = {};
  f32x4 acco[2][4] = {};

  // loop-carried staging pointers
  const u16* kp[2];
  const u16* vp[2];
#pragma unroll
  for (int i = 0; i < 2; ++i) {
    int c = tid + i * 256;
    int row = c >> 3, pp = c & 7;
    int pl = pp ^ (row & 7);  // pre-swizzled global source, linear LDS dest
    kp[i] = kb + hb + (size_t)row * 64 + pl * 8;       // += 4096 per tile
    vp[i] = vtb + hb + (size_t)row * 1024 + pl * 8;    // += 64 per tile
  }

  auto stage = [&](int bi) {
#pragma unroll
    for (int i = 0; i < 2; ++i) {
      int c = tid + i * 256;
      GLD16(kp[i], &Ks[bi][c * 8]);
      GLD16(vp[i], &Vs[bi][c * 8]);
      kp[i] += 4096;
      vp[i] += 64;
    }
  };

  stage(0);

  const float scale2 = 0.125f * 1.44269504f;

#pragma unroll 1
  for (int t = 0; t < 16; ++t) {
    const int cur = t & 1;
    u16 bn0[2], bn1[2];
    if (t < 15) {
      stage(cur ^ 1);
      // issue next tile's rel_h bias loads now; consumed next iteration
#pragma unroll
      for (int m = 0; m < 2; ++m) { bn0[m] = bp[m][-2]; bn1[m] = bp[m][-3]; }
      asm volatile("s_waitcnt vmcnt(8)" ::: "memory");
    } else {
      asm volatile("s_waitcnt vmcnt(0)" ::: "memory");
    }
    __builtin_amdgcn_sched_barrier(0);
    __builtin_amdgcn_s_barrier();        // entry: buf[cur] ready
    __builtin_amdgcn_sched_barrier(0);

    // QK^T (swapped): sac[m][f] col=lr -> q, row=lg*4+r -> k=f*16+lg*4+r
    f32x4 sac[2][4] = {};
    __builtin_amdgcn_s_setprio(1);
#pragma unroll
    for (int kf = 0; kf < 2; ++kf) {
#pragma unroll
      for (int f = 0; f < 4; ++f) {
        int row = f * 16 + lr;
        bf16x8 kv = *(const bf16x8*)&Ks[cur][(row * 64 + kf * 32 + lg * 8) ^ ((row & 7) << 3)];
#pragma unroll
        for (int m = 0; m < 2; ++m)
          sac[m][f] = __builtin_amdgcn_mfma_f32_16x16x32_bf16(kv, qf[m][kf], sac[m][f], 0, 0, 0);
      }
    }
    __builtin_amdgcn_s_setprio(0);

    // bias + exp2 + in-register P (A-frag via kappa order, zero cross-lane)
    bf16x8 paf[2][2];
#pragma unroll
    for (int m = 0; m < 2; ++m) {
      float c0 = bf2f(bc0[m]), c1 = bf2f(bc1[m]);
      float bs[2][2][4];  // [j = b0/b1][i][r]
#pragma unroll
      for (int i = 0; i < 2; ++i)
#pragma unroll
        for (int r = 0; r < 4; ++r) {
          bs[0][i][r] = c0 + rwv[m][i][r];
          bs[1][i][r] = c1 + rwv[m][i][r];
        }
      union { u32 w[4]; bf16x8 v; } wa, wb;
#pragma unroll
      for (int f = 0; f < 4; ++f) {
        const int j = (f >> 1) & 1, i = f & 1;
        float p0 = __builtin_amdgcn_exp2f(sac[m][f][0] * scale2 + bs[j][i][0]);
        float p1 = __builtin_amdgcn_exp2f(sac[m][f][1] * scale2 + bs[j][i][1]);
        float p2 = __builtin_amdgcn_exp2f(sac[m][f][2] * scale2 + bs[j][i][2]);
        float p3 = __builtin_amdgcn_exp2f(sac[m][f][3] * scale2 + bs[j][i][3]);
        lsum[m] += (p0 + p1) + (p2 + p3);
        u32 w0, w1;
        asm("v_cvt_pk_bf16_f32 %0, %1, %2" : "=v"(w0) : "v"(p0), "v"(p1));
        asm("v_cvt_pk_bf16_f32 %0, %1, %2" : "=v"(w1) : "v"(p2), "v"(p3));
        if (f < 2) { wa.w[f * 2] = w0; wa.w[f * 2 + 1] = w1; }
        else       { wb.w[(f - 2) * 2] = w0; wb.w[(f - 2) * 2 + 1] = w1; }
      }
      paf[m][0] = wa.v;
      paf[m][1] = wb.v;
    }

    // PV: O[q][d], acco row=lg*4+r -> q, col=lr -> d
    __builtin_amdgcn_s_setprio(1);
#pragma unroll
    for (int kf = 0; kf < 2; ++kf) {
#pragma unroll
      for (int fd = 0; fd < 4; ++fd) {
        int drow = fd * 16 + lr;
        bf16x8 vv = *(const bf16x8*)&Vs[cur][(drow * 64 + kf * 32 + lg * 8) ^ ((drow & 7) << 3)];
#pragma unroll
        for (int m = 0; m < 2; ++m)
          acco[m][fd] = __builtin_amdgcn_mfma_f32_16x16x32_bf16(paf[m][kf], vv, acco[m][fd], 0, 0, 0);
      }
    }
    __builtin_amdgcn_s_setprio(0);

    if (t < 15) {
#pragma unroll
      for (int m = 0; m < 2; ++m) {
        bc0[m] = bn0[m];
        bc1[m] = bn1[m];
        bp[m] -= 2;
      }
    }

    __builtin_amdgcn_sched_barrier(0);
    __builtin_amdgcn_s_barrier();        // exit: reads done before overwrite
    __builtin_amdgcn_sched_barrier(0);
  }

#pragma unroll
  for (int m = 0; m < 2; ++m) {
    float s = lsum[m];
    s += __shfl_xor(s, 16);
    s += __shfl_xor(s, 32);
    float inv = 1.0f / s;  // valid on lane with lr = q-local, any lg
#pragma unroll
    for (int r = 0; r < 4; ++r) {
      int src = (lane & 48) + ((lane & 48) >> 2) + r;
      float invr = __shfl(inv, src);
      int gq = q0 + m * 16 + lg * 4 + r;
#pragma unroll
      for (int fd = 0; fd < 4; ++fd)
        ao[hb + (size_t)gq * 64 + fd * 16 + lr] = f2bf(acco[m][fd][r] * invr);
    }
  }
}

// ---------------------------------------------------------------- launch
extern "C" void kernel_launch(void* const* d_in, const int* in_sizes, int n_in,
                              void* d_out, int out_size, void* d_ws, size_t ws_size,
                              hipStream_t stream) {
  const float* x = (const float*)d_in[0];
  const float* qkv_w = (const float*)d_in[1];
  const float* qkv_b = (const float*)d_in[2];
  const float* proj_w = (const float*)d_in[3];
  const float* proj_b = (const float*)d_in[4];
  const float* rel_pos_h = (const float*)d_in[5];
  const float* rel_pos_w = (const float*)d_in[6];
  float* out = (float*)d_out;

  char* ws = (char*)d_ws;
  u16* x_bf = (u16*)(ws + 0);              // 12,582,912 B (reused as attn out)
  u16* qkvw_bf = (u16*)(ws + 12582912);    //  3,538,944
  u16* projw_bf = (u16*)(ws + 16121856);   //  1,179,648
  u16* qbuf = (u16*)(ws + 17301504);       // 12,582,912
  u16* kbuf = (u16*)(ws + 29884416);       // 12,582,912
  u16* vtbuf = (u16*)(ws + 42467328);      // 12,582,912
  u16* pbuf = (u16*)(ws + 55050240);       // 25,165,824 (98304 x 128 bf16)
  u16* tbl = (u16*)(ws + 80216064);        //     16,384 -> total 80,232,448
  u16* aobuf = x_bf;                        // alias: x_bf dead after QKV gemm

  cvt_kernel<<<6144, 256, 0, stream>>>(x, x_bf, 6291456);
  cvt_kernel<<<1728, 256, 0, stream>>>(qkv_w, qkvw_bf, 1769472);
  cvt_kernel<<<576, 256, 0, stream>>>(proj_w, projw_bf, 589824);
  tbl_kernel<<<32, 256, 0, stream>>>(rel_pos_h, rel_pos_w, tbl);

  gemm128<0><<<dim3(18, 64), 256, 0, stream>>>(x_bf, qkvw_bf, qkv_b, qbuf, kbuf, vtbuf, nullptr);

  pgemm_kernel<<<768, 256, 0, stream>>>(qbuf, tbl, pbuf);

  attn_kernel<<<dim3(96, 8), 256, 0, stream>>>(qbuf, kbuf, vtbuf, pbuf, aobuf);

  gemm128<1><<<dim3(6, 64), 256, 0, stream>>>(aobuf, projw_bf, proj_b, nullptr, nullptr, nullptr, out);
}